// Round 7
// baseline (211.771 us; speedup 1.0000x reference)
//
#include <hip/hip_runtime.h>

// Boundary_binaryLoss: 15x15 binary morphology boundary + masked NLL mean.
// B=32, C=2, H=480, W=864 (=27*32). labels in {0,1,255}.
// valid = (lbl!=255) && win15x15 has (v==1) && win15x15 has (v!=1)
// loss = -sum(valid ? logits[b,lbl,h,w] : 0) / max(#valid,1)
//
// R1: atomics serialized -> partials. R2-R6: SIX structures all ~63-70us of
// device work; invariant was 128-256B scattered HBM touches (tile-width 256B /
// lane-per-row 128B @ 3456B stride) -> ~2 TB/s vs fill's 6.8 TB/s sequential.
// R7: all heavy traffic made perfectly sequential:
//   1) bitpack: labels -> A=(v==1), Ign=(v==255) bitmasks (sequential stream)
//   2) morph:   masks -> valid bitmask + per-wave counts (L2/L3-resident;
//               u64-SWAR horizontal OR, shuffle vertical OR, lane=row)
//   3) gather:  LINEAR sweep of logits [B,2,H,W]; block = 16KB contiguous
//               (fill-identical pattern); mask dwords L1-shared by 8 float4s
//   4) final:   reduce counts+sums

namespace {
constexpr int B_ = 32;
constexpr int H_ = 480;
constexpr int W_ = 864;
constexpr int NW = 27;                  // mask dwords per row
constexpr int NMASK = B_ * H_ * NW;     // 414,720 dwords = 1.66 MB
constexpr int SROWS = 50;               // rows per morph wave (lanes 7..56)
constexpr int NSTRIP = 10;              // ceil(480/50)
constexpr int NWAVE_M = B_ * NW * NSTRIP;  // 8640 morph waves
constexpr int NBLK_M = NWAVE_M / 4;        // 2160
constexpr int NF4 = B_ * 2 * H_ * W_ / 4;  // 6,635,520 float4s
constexpr int NBLK_G = NF4 / 1024;         // 6480 gather blocks (16KB each)
constexpr int NWAVE_G = NBLK_G * 4;        // 25,920 sum partials
constexpr size_t OFF_IGN  = 2u << 20;   // d_ws byte offsets
constexpr size_t OFF_VAL  = 4u << 20;
constexpr size_t OFF_CNT  = 6u << 20;   // 8640 floats
constexpr size_t OFF_SUM  = 7u << 20;   // 25,920 floats
} // namespace

// ---------------- 1) bitpack labels (sequential stream) ----------------
extern "C" __global__ __launch_bounds__(256)
void bl_bitpack(const int* __restrict__ labels,
                unsigned* __restrict__ Am, unsigned* __restrict__ Im)
{
  const int t = blockIdx.x * 256 + threadIdx.x;   // one mask dword per thread
  const int4* p = (const int4*)(labels + (size_t)t * 32);
  unsigned a = 0, ig = 0;
#pragma unroll
  for (int k = 0; k < 8; ++k) {
    const int4 v = p[k];
    a  |= ((v.x == 1)   ? 1u : 0u) << (4 * k) | ((v.y == 1)   ? 2u : 0u) << (4 * k)
       |  ((v.z == 1)   ? 4u : 0u) << (4 * k) | ((v.w == 1)   ? 8u : 0u) << (4 * k);
    ig |= ((v.x == 255) ? 1u : 0u) << (4 * k) | ((v.y == 255) ? 2u : 0u) << (4 * k)
       |  ((v.z == 255) ? 4u : 0u) << (4 * k) | ((v.w == 255) ? 8u : 0u) << (4 * k);
  }
  Am[t] = a;
  Im[t] = ig;
}

// horizontal 15-wide OR; w0/w1/w2 = left/center/right mask dwords
__device__ __forceinline__ unsigned hwin(unsigned w0, unsigned w1, unsigned w2) {
  unsigned long long L = ((unsigned long long)w1 << 32) | w0;
  unsigned long long R = ((unsigned long long)w2 << 32) | w1;
  L |= L << 1; L |= L << 2; L |= L << 4;   // bit k |= bits k-7..k
  R |= R >> 1; R |= R >> 2; R |= R >> 4;   // bit k |= bits k..k+7
  return (unsigned)(L >> 32) | (unsigned)R;
}

// vertical 15-wide OR across lanes (lane = row)
__device__ __forceinline__ unsigned vwin(unsigned x) {
  unsigned u = x, d = x;
  u |= __shfl_up(u, 1, 64);  u |= __shfl_up(u, 2, 64);  u |= __shfl_up(u, 4, 64);
  d |= __shfl_down(d, 1, 64); d |= __shfl_down(d, 2, 64); d |= __shfl_down(d, 4, 64);
  return u | d;
}

// ---------------- 2) morphology -> valid masks + counts ----------------
extern "C" __global__ __launch_bounds__(256)
void bl_morph(const unsigned* __restrict__ Am, const unsigned* __restrict__ Im,
              unsigned* __restrict__ Vm, float* __restrict__ cnt_part)
{
  const int tid = threadIdx.x;
  const int lane = tid & 63;
  const int wid = blockIdx.x * 4 + (tid >> 6);   // 0..8639
  const int b = wid / (NW * NSTRIP);
  const int rem = wid - b * (NW * NSTRIP);
  const int dc = rem / NSTRIP;                   // dword-column 0..26
  const int s = rem - dc * NSTRIP;               // row strip 0..9

  const int gr = SROWS * s - 7 + lane;           // this lane's row
  const bool inrow = (gr >= 0) && (gr < H_);
  const bool out_lane = (lane >= 7) && (lane <= 56) && (gr < H_);

  unsigned A0 = 0, A1 = 0, A2 = 0, Ic = 0;
  size_t rbase = 0;
  if (inrow) {
    rbase = ((size_t)b * H_ + gr) * NW + dc;
    A1 = Am[rbase];
    Ic = Im[rbase];
    if (dc > 0) A0 = Am[rbase - 1];
    if (dc < NW - 1) A2 = Am[rbase + 1];
  }
  const unsigned N0 = (inrow && dc > 0) ? ~A0 : 0u;
  const unsigned N1 = inrow ? ~A1 : 0u;
  const unsigned N2 = (inrow && dc < NW - 1) ? ~A2 : 0u;

  const unsigned vA = vwin(hwin(A0, A1, A2));   // window contains v==1
  const unsigned vN = vwin(hwin(N0, N1, N2));   // window contains v!=1
  const unsigned valid = out_lane ? (vA & vN & ~Ic) : 0u;

  if (out_lane) Vm[rbase] = valid;

  unsigned lcnt = __popc(valid);
#pragma unroll
  for (int off = 32; off > 0; off >>= 1) lcnt += __shfl_down(lcnt, off, 64);
  if (lane == 0) cnt_part[wid] = (float)lcnt;
}

// ---------------- 3) gather: linear logits sweep ----------------
extern "C" __global__ __launch_bounds__(256)
void bl_gather(const float* __restrict__ logits,
               const unsigned* __restrict__ Am, const unsigned* __restrict__ Vm,
               float* __restrict__ sum_part)
{
  const int tid = threadIdx.x;
  float lsum = 0.f;
#pragma unroll
  for (int it = 0; it < 4; ++it) {
    const int g = blockIdx.x * 1024 + it * 256 + tid;  // float4 index, < NF4
    const float4 v = *(const float4*)(logits + (size_t)g * 4);
    const int row = g / 216;          // (b,c,h) row id; 216 float4s per row
    const int col4 = g - row * 216;
    const int col = col4 * 4;
    const int b = row / 960;          // 2*480 rows per image
    const int remr = row - b * 960;
    const int c = remr / 480;
    const int h = remr - c * 480;
    const size_t mi = ((size_t)b * H_ + h) * NW + (col >> 5);
    const unsigned vm = Vm[mi];
    const unsigned am = Am[mi];
    const unsigned want = c ? (vm & am) : (vm & ~am);
    const unsigned sel = (want >> (col & 31)) & 0xFu;
    lsum += (sel & 1u) ? v.x : 0.f;
    lsum += (sel & 2u) ? v.y : 0.f;
    lsum += (sel & 4u) ? v.z : 0.f;
    lsum += (sel & 8u) ? v.w : 0.f;
  }
#pragma unroll
  for (int off = 32; off > 0; off >>= 1) lsum += __shfl_down(lsum, off, 64);
  if ((tid & 63) == 0) sum_part[blockIdx.x * 4 + (tid >> 6)] = lsum;
}

// ---------------- 4) final reduction ----------------
extern "C" __global__ __launch_bounds__(1024)
void bl_final(const float* __restrict__ cnt_part,
              const float* __restrict__ sum_part, float* __restrict__ out)
{
  __shared__ double red_s[16];
  __shared__ double red_c[16];
  const int tid = threadIdx.x;
  double s = 0.0, cc = 0.0;
  for (int i = tid; i < NWAVE_G; i += 1024) s += (double)sum_part[i];
  for (int i = tid; i < NWAVE_M; i += 1024) cc += (double)cnt_part[i];
#pragma unroll
  for (int off = 32; off > 0; off >>= 1) {
    s += __shfl_down(s, off, 64);
    cc += __shfl_down(cc, off, 64);
  }
  const int wave = tid >> 6;
  if ((tid & 63) == 0) { red_s[wave] = s; red_c[wave] = cc; }
  __syncthreads();
  if (tid == 0) {
    double ts = 0.0, tc = 0.0;
#pragma unroll
    for (int i = 0; i < 16; ++i) { ts += red_s[i]; tc += red_c[i]; }
    if (tc < 1.0) tc = 1.0;
    out[0] = (float)(-ts / tc);
  }
}

extern "C" void kernel_launch(void* const* d_in, const int* in_sizes, int n_in,
                              void* d_out, int out_size, void* d_ws, size_t ws_size,
                              hipStream_t stream)
{
  const float* logits = (const float*)d_in[0];
  const int* labels = (const int*)d_in[1];
  float* out = (float*)d_out;
  unsigned* Am = (unsigned*)d_ws;
  unsigned* Im = (unsigned*)((char*)d_ws + OFF_IGN);
  unsigned* Vm = (unsigned*)((char*)d_ws + OFF_VAL);
  float* cnt_part = (float*)((char*)d_ws + OFF_CNT);
  float* sum_part = (float*)((char*)d_ws + OFF_SUM);
  // every d_ws slot used is fully rewritten each call -> 0xAA poison harmless

  bl_bitpack<<<NMASK / 256, 256, 0, stream>>>(labels, Am, Im);
  bl_morph<<<NBLK_M, 256, 0, stream>>>(Am, Im, Vm, cnt_part);
  bl_gather<<<NBLK_G, 256, 0, stream>>>(logits, Am, Vm, sum_part);
  bl_final<<<1, 1024, 0, stream>>>(cnt_part, sum_part, out);
}

// Round 8
// 206.344 us; speedup vs baseline: 1.0263x; 1.0263x over previous
//
#include <hip/hip_runtime.h>

// Boundary_binaryLoss: 15x15 binary morphology boundary + masked NLL mean.
// B=32, C=2, H=480, W=864 (=27*32). labels in {0,1,255}.
// valid = (lbl!=255) && win15x15 has (v==1) && win15x15 has (v!=1)
// loss = -sum(valid ? logits[b,lbl,h,w] : 0) / max(#valid,1)
//
// History: R1 atomics serialized (180us). R2-R6: every block-internal
// restructure neutral (~63us logits reader). R7: perfectly-linear gather ALSO
// ~2TB/s -> access pattern falsified as the limiter. R8 discriminates the two
// remaining theories: per-float4 loop overhead (divs + 2 scattered mask loads)
// vs a hard pure-read BW ceiling. Gather hot loop is now minimal: 1 NT float4
// load + 1 contiguous selector-byte load + 4 cndmask-adds. Selector bytes
// (one per float4, 6.6MB) are precomputed by bl_expand from the valid masks.
// Bitpack rewritten coalesced (contiguous int4 per lane + shfl-xor butterfly).

namespace {
constexpr int B_ = 32;
constexpr int H_ = 480;
constexpr int W_ = 864;
constexpr int NW = 27;                     // mask dwords per row
constexpr int NMASK = B_ * H_ * NW;        // 414,720 dwords = 1.66 MB
constexpr int SROWS = 50;                  // rows per morph wave (lanes 7..56)
constexpr int NSTRIP = 10;                 // ceil(480/50)
constexpr int NWAVE_M = B_ * NW * NSTRIP;  // 8640 morph waves
constexpr int NBLK_M = NWAVE_M / 4;        // 2160
constexpr int NF4 = B_ * 2 * H_ * W_ / 4;  // 6,635,520 float4s
constexpr int NBLK_G = NF4 / 1024;         // 6480 gather blocks
constexpr int NWAVE_G = NBLK_G * 4;        // 25,920 sum partials
constexpr int NBLK_P = NMASK / 32;         // 12960 bitpack blocks (8 dwords/wave)
constexpr size_t OFF_IM  = 2u << 20;
constexpr size_t OFF_VM  = 4u << 20;
constexpr size_t OFF_CNT = 6u << 20;   // 8640 floats
constexpr size_t OFF_SEL = 8u << 20;   // 6.64 MB selector bytes
constexpr size_t OFF_SUM = 16u << 20;  // 25,920 floats
} // namespace

typedef float f4v __attribute__((ext_vector_type(4)));

// ---------------- 1) bitpack labels (coalesced + butterfly pack) ----------
extern "C" __global__ __launch_bounds__(256)
void bl_bitpack(const int* __restrict__ labels,
                unsigned* __restrict__ Am, unsigned* __restrict__ Im)
{
  const int tid = threadIdx.x;
  const int lane = tid & 63;
  const int wid = blockIdx.x * 4 + (tid >> 6);       // wave chunk id
  // lane loads 4 CONSECUTIVE labels; wave covers 256 labels = 1KB contiguous
  const int4 v = *(const int4*)(labels + (size_t)wid * 256 + lane * 4);
  const unsigned nibA = (v.x == 1 ? 1u : 0u) | (v.y == 1 ? 2u : 0u) |
                        (v.z == 1 ? 4u : 0u) | (v.w == 1 ? 8u : 0u);
  const unsigned nibI = (v.x == 255 ? 1u : 0u) | (v.y == 255 ? 2u : 0u) |
                        (v.z == 255 ? 4u : 0u) | (v.w == 255 ? 8u : 0u);
  unsigned long long x = (unsigned long long)nibA |
                         ((unsigned long long)nibI << 32);
  // butterfly: group of 8 lanes -> full 32-bit masks in A half / I half
  unsigned long long p = __shfl_xor(x, 1, 64);
  x = (lane & 1) ? (p | (x << 4)) : (x | (p << 4));
  p = __shfl_xor(x, 2, 64);
  x = (lane & 2) ? (p | (x << 8)) : (x | (p << 8));
  p = __shfl_xor(x, 4, 64);
  x = (lane & 4) ? (p | (x << 16)) : (x | (p << 16));
  if ((lane & 7) == 0) {
    const int di = wid * 8 + (lane >> 3);
    Am[di] = (unsigned)x;
    Im[di] = (unsigned)(x >> 32);
  }
}

// horizontal 15-wide OR; w0/w1/w2 = left/center/right mask dwords
__device__ __forceinline__ unsigned hwin(unsigned w0, unsigned w1, unsigned w2) {
  unsigned long long L = ((unsigned long long)w1 << 32) | w0;
  unsigned long long R = ((unsigned long long)w2 << 32) | w1;
  L |= L << 1; L |= L << 2; L |= L << 4;   // bit k |= bits k-7..k
  R |= R >> 1; R |= R >> 2; R |= R >> 4;   // bit k |= bits k..k+7
  return (unsigned)(L >> 32) | (unsigned)R;
}

// vertical 15-wide OR across lanes (lane = row)
__device__ __forceinline__ unsigned vwin(unsigned x) {
  unsigned u = x, d = x;
  u |= __shfl_up(u, 1, 64);  u |= __shfl_up(u, 2, 64);  u |= __shfl_up(u, 4, 64);
  d |= __shfl_down(d, 1, 64); d |= __shfl_down(d, 2, 64); d |= __shfl_down(d, 4, 64);
  return u | d;
}

// ---------------- 2) morphology -> valid masks + counts ----------------
extern "C" __global__ __launch_bounds__(256)
void bl_morph(const unsigned* __restrict__ Am, const unsigned* __restrict__ Im,
              unsigned* __restrict__ Vm, float* __restrict__ cnt_part)
{
  const int tid = threadIdx.x;
  const int lane = tid & 63;
  const int wid = blockIdx.x * 4 + (tid >> 6);   // 0..8639
  const int b = wid / (NW * NSTRIP);
  const int rem = wid - b * (NW * NSTRIP);
  const int dc = rem / NSTRIP;
  const int s = rem - dc * NSTRIP;

  const int gr = SROWS * s - 7 + lane;
  const bool inrow = (gr >= 0) && (gr < H_);
  const bool out_lane = (lane >= 7) && (lane <= 56) && (gr < H_);

  unsigned A0 = 0, A1 = 0, A2 = 0, Ic = 0;
  size_t rbase = 0;
  if (inrow) {
    rbase = ((size_t)b * H_ + gr) * NW + dc;
    A1 = Am[rbase];
    Ic = Im[rbase];
    if (dc > 0) A0 = Am[rbase - 1];
    if (dc < NW - 1) A2 = Am[rbase + 1];
  }
  const unsigned N0 = (inrow && dc > 0) ? ~A0 : 0u;
  const unsigned N1 = inrow ? ~A1 : 0u;
  const unsigned N2 = (inrow && dc < NW - 1) ? ~A2 : 0u;

  const unsigned vA = vwin(hwin(A0, A1, A2));
  const unsigned vN = vwin(hwin(N0, N1, N2));
  const unsigned valid = out_lane ? (vA & vN & ~Ic) : 0u;

  if (out_lane) Vm[rbase] = valid;

  unsigned lcnt = __popc(valid);
#pragma unroll
  for (int off = 32; off > 0; off >>= 1) lcnt += __shfl_down(lcnt, off, 64);
  if (lane == 0) cnt_part[wid] = (float)lcnt;
}

// nibble j of x -> byte j of result
__device__ __forceinline__ unsigned long long spread(unsigned w) {
  unsigned long long x = w;
  x = (x | (x << 16)) & 0x0000FFFF0000FFFFull;
  x = (x | (x << 8))  & 0x00FF00FF00FF00FFull;
  x = (x | (x << 4))  & 0x0F0F0F0F0F0F0F0Full;
  return x;
}

// ---------------- 3) expand masks -> per-float4 selector bytes ----------
extern "C" __global__ __launch_bounds__(256)
void bl_expand(const unsigned* __restrict__ Am, const unsigned* __restrict__ Vm,
               unsigned long long* __restrict__ sel8)
{
  const int t = blockIdx.x * 256 + threadIdx.x;   // one mask dword
  const unsigned v = Vm[t];
  const unsigned a = Am[t];
  const int b = t / (H_ * NW);
  const int r2 = t - b * (H_ * NW);
  const int h = r2 / NW;
  const int dc = r2 - h * NW;
  // sel8 index = byte_offset/8: row (b,c,h) has 216 bytes = 27 u64s
  const size_t s0 = ((size_t)(b * 2 * H_ + h)) * NW + dc;
  sel8[s0] = spread(v & ~a);                       // channel 0 wants ~A
  sel8[s0 + (size_t)H_ * NW] = spread(v & a);      // channel 1 wants A
}

// ---------------- 4) gather: minimal streaming loop ----------------
extern "C" __global__ __launch_bounds__(256)
void bl_gather(const float* __restrict__ logits,
               const unsigned char* __restrict__ sel,
               float* __restrict__ sum_part)
{
  const int tid = threadIdx.x;
  float lsum = 0.f;
#pragma unroll
  for (int it = 0; it < 4; ++it) {
    const int g = blockIdx.x * 1024 + it * 256 + tid;   // float4 index
    const f4v v = __builtin_nontemporal_load((const f4v*)(logits + (size_t)g * 4));
    const unsigned s = sel[g];
    lsum += (s & 1u) ? v.x : 0.f;
    lsum += (s & 2u) ? v.y : 0.f;
    lsum += (s & 4u) ? v.z : 0.f;
    lsum += (s & 8u) ? v.w : 0.f;
  }
#pragma unroll
  for (int off = 32; off > 0; off >>= 1) lsum += __shfl_down(lsum, off, 64);
  if ((tid & 63) == 0) sum_part[blockIdx.x * 4 + (tid >> 6)] = lsum;
}

// ---------------- 5) final reduction ----------------
extern "C" __global__ __launch_bounds__(1024)
void bl_final(const float* __restrict__ cnt_part,
              const float* __restrict__ sum_part, float* __restrict__ out)
{
  __shared__ double red_s[16];
  __shared__ double red_c[16];
  const int tid = threadIdx.x;
  double s = 0.0, cc = 0.0;
  for (int i = tid; i < NWAVE_G; i += 1024) s += (double)sum_part[i];
  for (int i = tid; i < NWAVE_M; i += 1024) cc += (double)cnt_part[i];
#pragma unroll
  for (int off = 32; off > 0; off >>= 1) {
    s += __shfl_down(s, off, 64);
    cc += __shfl_down(cc, off, 64);
  }
  const int wave = tid >> 6;
  if ((tid & 63) == 0) { red_s[wave] = s; red_c[wave] = cc; }
  __syncthreads();
  if (tid == 0) {
    double ts = 0.0, tc = 0.0;
#pragma unroll
    for (int i = 0; i < 16; ++i) { ts += red_s[i]; tc += red_c[i]; }
    if (tc < 1.0) tc = 1.0;
    out[0] = (float)(-ts / tc);
  }
}

extern "C" void kernel_launch(void* const* d_in, const int* in_sizes, int n_in,
                              void* d_out, int out_size, void* d_ws, size_t ws_size,
                              hipStream_t stream)
{
  const float* logits = (const float*)d_in[0];
  const int* labels = (const int*)d_in[1];
  float* out = (float*)d_out;
  unsigned* Am = (unsigned*)d_ws;
  unsigned* Im = (unsigned*)((char*)d_ws + OFF_IM);
  unsigned* Vm = (unsigned*)((char*)d_ws + OFF_VM);
  float* cnt_part = (float*)((char*)d_ws + OFF_CNT);
  unsigned long long* sel8 = (unsigned long long*)((char*)d_ws + OFF_SEL);
  float* sum_part = (float*)((char*)d_ws + OFF_SUM);
  // every d_ws slot used is fully rewritten each call -> 0xAA poison harmless

  bl_bitpack<<<NBLK_P, 256, 0, stream>>>(labels, Am, Im);
  bl_morph<<<NBLK_M, 256, 0, stream>>>(Am, Im, Vm, cnt_part);
  bl_expand<<<NMASK / 256, 256, 0, stream>>>(Am, Vm, sel8);
  bl_gather<<<NBLK_G, 256, 0, stream>>>(logits, (const unsigned char*)sel8, sum_part);
  bl_final<<<1, 1024, 0, stream>>>(cnt_part, sum_part, out);
}